// Round 8
// baseline (612.355 us; speedup 1.0000x reference)
//
#include <hip/hip_runtime.h>
#include <hip/hip_bf16.h>

#define D 128
typedef unsigned short u16;
typedef unsigned int u32;
typedef _Float16 h2 __attribute__((ext_vector_type(2)));
typedef _Float16 f16x8 __attribute__((ext_vector_type(8)));
typedef float f32x4 __attribute__((ext_vector_type(4)));

__device__ __forceinline__ float bf2f(u16 u) {
    return __uint_as_float(((u32)u) << 16);
}
__device__ __forceinline__ u16 f2bf(float f) {
    union { float f; u32 u; } a; a.f = f;
    u32 r = (a.u + 0x7FFF + ((a.u >> 16) & 1)) >> 16;   // RNE
    return (u16)r;
}
__device__ __forceinline__ u16 f2h(float f) {
    union { _Float16 h; u16 u; } c; c.h = (_Float16)f;
    return c.u;
}
__device__ __forceinline__ h2 u2h2(u32 v) {
    union { u32 u; h2 h; } c; c.u = v;
    return c.h;
}
__device__ __forceinline__ u32 h22u(h2 h) {
    union { u32 u; h2 h; } c; c.h = h;
    return c.u;
}
__device__ __forceinline__ u32 packh2(float a, float b) {
    return (u32)f2h(a) | ((u32)f2h(b) << 16);
}
__device__ __forceinline__ float hdot2(h2 a, h2 b, float c) {
#if __has_builtin(__builtin_amdgcn_fdot2)
    return __builtin_amdgcn_fdot2(a, b, c, false);
#else
    return (float)a.x * (float)b.x + (float)a.y * (float)b.y + c;
#endif
}
// flag-dependent raw-input access (epilogue / prep only)
__device__ __forceinline__ float ldIn(const void* p, size_t i, int isBf) {
    return isBf ? bf2f(((const u16*)p)[i]) : ((const float*)p)[i];
}
__device__ __forceinline__ void stOut(void* p, size_t i, float v, int isBf) {
    if (isBf) ((u16*)p)[i] = f2bf(v);
    else      ((float*)p)[i] = v;
}

// ---------------- dtype sniffer --------------------------------------------
__global__ void sniff_k(const u16* __restrict__ probe, int* __restrict__ flag) {
    int t = threadIdx.x;           // 64 threads
    u16 v = probe[2 * t];
    int ex = (v >> 7) & 0xFF;
    int sane = (ex == 0) || (ex >= 0x70 && ex <= 0x8A);
    unsigned long long m = __ballot(sane != 0);
    if (t == 0) *flag = (__popcll(m) >= 48) ? 1 : 0;
}

// ---------------- convert raw input -> canonical f16 ------------------------
__global__ void convert_h_k(const void* __restrict__ src, u16* __restrict__ dst,
                            int n, const int* __restrict__ flagp) {
    int i = blockIdx.x * blockDim.x + threadIdx.x;
    int isBf = *flagp;
    if (i < n) dst[i] = f2h(ldIn(src, i, isBf));
}
// entity emb: fill contiguous eeb AND PE E-slots
// PE u16 layout per ent (256 u16): lane l -> [4l]=P(2l) [4l+1]=P(2l+1)
//                                            [4l+2]=E(2l) [4l+3]=E(2l+1)
__global__ void convert_e_k(const void* __restrict__ src, u16* __restrict__ eeb,
                            u16* __restrict__ PE, int n, const int* __restrict__ flagp) {
    int i = blockIdx.x * blockDim.x + threadIdx.x;
    int isBf = *flagp;
    if (i < n) {
        u16 h = f2h(ldIn(src, i, isBf));
        eeb[i] = h;
        int ent = i >> 7, c = i & 127;
        PE[(size_t)ent * 256 + ((c >> 1) << 2) + 2 + (c & 1)] = h;
    }
}
// refresh PE E-slots from eL1 pairs (between layers)
__global__ void packE_k(const u32* __restrict__ eL1p, u32* __restrict__ PEu, int n64) {
    int i = blockIdx.x * blockDim.x + threadIdx.x;   // n64 = nE*64 pair slots
    if (i < n64) PEu[(size_t)(i >> 6) * 128 + 2 * (i & 63) + 1] = eL1p[i];
}

// ---------------- CSR build -------------------------------------------------
__global__ void zero_k(int* __restrict__ p, int n) {
    int i = blockIdx.x * blockDim.x + threadIdx.x;
    if (i < n) p[i] = 0;
}
__global__ void hist_k(const int* __restrict__ keys, int n, int nDst,
                       int* __restrict__ cntP1) {
    int i = blockIdx.x * blockDim.x + threadIdx.x;
    if (i < n) {
        int k = min(max(keys[i], 0), nDst - 1);
        atomicAdd(&cntP1[k + 1], 1);
    }
}
__global__ void copy_k(const int* __restrict__ src, int* __restrict__ dst, int n) {
    int i = blockIdx.x * blockDim.x + threadIdx.x;
    if (i < n) dst[i] = src[i];
}
// entity scatter: payload = tail | (rtype<<24), fully clamped at build
__global__ void scatter_e(const int* __restrict__ head, const int* __restrict__ tail,
                          const int* __restrict__ etyp, int n, int nDst, int nEnt,
                          int* __restrict__ pos, int* __restrict__ pack) {
    int i = blockIdx.x * blockDim.x + threadIdx.x;
    if (i < n) {
        int k = min(max(head[i], 0), nDst - 1);
        int p = atomicAdd(&pos[k], 1);
        if (p >= 0 && p < n) {
            int tl = min(max(tail[i], 0), nEnt - 1);
            int rt = min(max(etyp[i] - 1, 0), 9);
            pack[p] = tl | (rt << 24);
        }
    }
}
// user scatter: payload = (item, weight)
__global__ void scatter_u(const int* __restrict__ u_idx, const int* __restrict__ i_idx,
                          const void* __restrict__ iw, int n, int nDst, int nEnt,
                          int* __restrict__ pos, int* __restrict__ item,
                          float* __restrict__ wt, const int* __restrict__ flagp) {
    int i = blockIdx.x * blockDim.x + threadIdx.x;
    int isBf = *flagp;
    if (i < n) {
        int k = min(max(u_idx[i], 0), nDst - 1);
        int p = atomicAdd(&pos[k], 1);
        if (p >= 0 && p < n) {
            item[p] = min(max(i_idx[i], 0), nEnt - 1);
            wt[p] = ldIn(iw, i, isBf);
        }
    }
}

// ---------------- multi-block scan over buf[1..n] ---------------------------
__global__ __launch_bounds__(256) void block_sum_k(const int* __restrict__ buf, int n,
                                                   int* __restrict__ bsum) {
    __shared__ int waveTot[4];
    int b = blockIdx.x, t = threadIdx.x, lane = t & 63, wave = t >> 6;
    int idx = 1 + b * 1024 + t * 4;
    int s = 0;
    #pragma unroll
    for (int k = 0; k < 4; ++k)
        if (idx + k <= n) s += buf[idx + k];
    #pragma unroll
    for (int o = 32; o > 0; o >>= 1) s += __shfl_xor(s, o);
    if (lane == 0) waveTot[wave] = s;
    __syncthreads();
    if (t == 0) bsum[b] = waveTot[0] + waveTot[1] + waveTot[2] + waveTot[3];
}
__global__ void scan_bsums_k(int* __restrict__ bsum, int nb) {
    int t = threadIdx.x;   // 64 threads
    int v = (t < nb) ? bsum[t] : 0;
    int x = v;
    #pragma unroll
    for (int o = 1; o < 64; o <<= 1) {
        int y = __shfl_up(x, o);
        if (t >= o) x += y;
    }
    if (t < nb) bsum[t] = x - v;   // exclusive
}
__global__ __launch_bounds__(256) void block_scan_k(int* __restrict__ buf, int n,
                                                    const int* __restrict__ bsum) {
    __shared__ int waveTot[4];
    int b = blockIdx.x, t = threadIdx.x, lane = t & 63, wave = t >> 6;
    int idx = 1 + b * 1024 + t * 4;
    int v0 = 0, v1 = 0, v2 = 0, v3 = 0;
    if (idx     <= n) v0 = buf[idx];
    if (idx + 1 <= n) v1 = buf[idx + 1];
    if (idx + 2 <= n) v2 = buf[idx + 2];
    if (idx + 3 <= n) v3 = buf[idx + 3];
    int s = v0 + v1 + v2 + v3;
    int x = s;
    #pragma unroll
    for (int o = 1; o < 64; o <<= 1) {
        int y = __shfl_up(x, o);
        if (lane >= o) x += y;
    }
    if (lane == 63) waveTot[wave] = x;
    __syncthreads();
    int off = bsum[b];
    for (int wv = 0; wv < wave; ++wv) off += waveTot[wv];
    int r0 = off + (x - s) + v0;
    int r1 = r0 + v1;
    int r2 = r1 + v2;
    int r3 = r2 + v3;
    if (idx     <= n) buf[idx]     = r0;
    if (idx + 1 <= n) buf[idx + 1] = r1;
    if (idx + 2 <= n) buf[idx + 2] = r2;
    if (idx + 3 <= n) buf[idx + 3] = r3;
}

// ---------------- P = E @ W_Q via MFMA (f16), C written into PE P-slots -----
// mfma_f32_16x16x32_f16; layouts per HW-verified guide §3.
#define GEMM_ROWS 64
#define WT_STRIDE 136   // u16 stride: 68-dword lane stride -> 2-way alias (free)
__global__ __launch_bounds__(256) void gemm_P4(const u16* __restrict__ E,
                                               const u16* __restrict__ WQ,
                                               u16* __restrict__ PE, int nRows) {
    __shared__ u16 sWT[D * WT_STRIDE];   // 34 KiB, W transposed: sWT[c][k]
    int t = threadIdx.x;
    for (int i = t; i < D * D; i += 256) {
        int k = i >> 7, c = i & 127;     // WQ[k][c] coalesced read
        sWT[c * WT_STRIDE + k] = WQ[i];
    }
    __syncthreads();
    int wave = t >> 6, lane = t & 63;
    int m = lane & 15, quad = lane >> 4;
    int row0 = blockIdx.x * GEMM_ROWS + wave * 16;
    int rowA = min(row0 + m, nRows - 1);
    const u16* erow = E + (size_t)rowA * D;
    f16x8 afrag[4];
    #pragma unroll
    for (int ks = 0; ks < 4; ++ks)
        afrag[ks] = *(const f16x8*)(erow + ks * 32 + quad * 8);
    #pragma unroll
    for (int ct = 0; ct < 8; ++ct) {
        f32x4 acc = {0.f, 0.f, 0.f, 0.f};
        const u16* wcol = sWT + (ct * 16 + m) * WT_STRIDE + quad * 8;
        #pragma unroll
        for (int ks = 0; ks < 4; ++ks) {
            f16x8 bfrag = *(const f16x8*)(wcol + ks * 32);
            acc = __builtin_amdgcn_mfma_f32_16x16x32_f16(afrag[ks], bfrag, acc, 0, 0, 0);
        }
        int c = ct * 16 + m;
        size_t pbase = ((size_t)(c >> 1) << 2) + (c & 1);   // P-slot within row
        #pragma unroll
        for (int reg = 0; reg < 4; ++reg) {
            int r = row0 + quad * 4 + reg;
            if (r < nRows) PE[(size_t)r * 256 + pbase] = f2h(acc[reg]);
        }
    }
}

// ---------------- fused attention + aggregate + l2norm (+ mean epilogue) ----
// One wave per entity. lane l holds dims {2l, 2l+1}; lanes 0-31 = head 0,
// lanes 32-63 = head 1. Per edge: ONE 8B gather (P-pair + E-pair interleaved),
// f16 packed mul + fdot2, softmax without running max (|s| << 80).
__global__ __launch_bounds__(256) void entity_agg4(
    const uint2* __restrict__ PE, const u16* __restrict__ relh,
    const int* __restrict__ e_off, const int* __restrict__ e_pack,
    u32* __restrict__ eL1p,                 // layer-1 out (contig pairs)
    const u32* __restrict__ eebp,           // layer-2: eeb pairs (epilogue)
    void* __restrict__ outE, int finalMode, size_t outElemOff,
    int nEnt, const int* __restrict__ flagp) {
    __shared__ u32 sRel[10 * 64];   // 2.5 KiB, f16 pairs
    int tid = threadIdx.x;
    for (int i = tid; i < 10 * 64; i += 256) sRel[i] = ((const u32*)relh)[i];
    __syncthreads();
    int wid = (blockIdx.x * blockDim.x + tid) >> 6;
    int lane = tid & 63;
    if (wid >= nEnt) return;
    const u32* PEu = (const u32*)PE;
    h2 q = u2h2(PEu[(size_t)wid * 128 + 2 * lane]);       // P-pair of wid
    const float SC = 0.125f * 1.44269504f;   // /sqrt(64) folded with log2(e)
    float l = 0.f, a0 = 0.f, a1 = 0.f;
    int s = e_off[wid], e = e_off[wid + 1];
    for (int j0 = s; j0 < e; j0 += 64) {
        int B = min(64, e - j0);
        int pk = (lane < B) ? e_pack[j0 + lane] : 0;
        int pv = __shfl(pk, 0);
        uint2 pe = PE[(size_t)(pv & 0xFFFFFF) * 64 + lane];
        for (int i = 0; i < B; ++i) {
            uint2 cpe = pe;
            int cpv = pv;
            if (i + 1 < B) {                       // prefetch next edge's row
                pv = __shfl(pk, i + 1);
                pe = PE[(size_t)(pv & 0xFFFFFF) * 64 + lane];
            }
            int rt = (int)((u32)cpv >> 24);        // clamped to [0,9] at build
            h2 rr = u2h2(sRel[rt * 64 + lane]);
            h2 pt = u2h2(cpe.x);
            h2 ev = u2h2(cpe.y);
            h2 kq = pt * rr;                       // v_pk_mul_f16
            h2 v  = ev * rr;                       // v_pk_mul_f16
            float prod = hdot2(q, kq, 0.f);        // v_dot2_f32_f16
            #pragma unroll
            for (int o = 16; o > 0; o >>= 1) prod += __shfl_xor(prod, o);
            float p = exp2f(prod * SC);            // v_exp_f32
            l += p;
            a0 = fmaf(p, (float)v.x, a0);
            a1 = fmaf(p, (float)v.y, a1);
        }
    }
    float o0 = (l > 0.f) ? a0 / l : 0.f;
    float o1 = (l > 0.f) ? a1 / l : 0.f;
    float ss = o0 * o0 + o1 * o1;
    #pragma unroll
    for (int o = 32; o > 0; o >>= 1) ss += __shfl_xor(ss, o);
    float inv = 1.f / fmaxf(sqrtf(ss), 1e-12f);
    float w0 = o0 * inv, w1 = o1 * inv;
    size_t pri = (size_t)wid * 64 + lane;
    if (finalMode) {
        int isBf = *flagp;
        const float k = 1.0f / 3.0f;
        h2 ec = u2h2(PEu[(size_t)wid * 128 + 2 * lane + 1]);  // eL1 (E-slot)
        h2 e0 = u2h2(eebp[pri]);                              // eeb pair
        w0 = ((float)e0.x + (float)ec.x + w0) * k;
        w1 = ((float)e0.y + (float)ec.y + w1) * k;
        size_t be = outElemOff + (size_t)wid * D + 2 * lane;
        stOut(outE, be, w0, isBf);
        stOut(outE, be + 1, w1, isBf);
    } else {
        eL1p[pri] = packh2(w0, w1);
    }
}

// ---------------- user aggregation (2-deep prefetch, f16 pairs) -------------
__global__ __launch_bounds__(256) void user_agg4(
    const u32* __restrict__ eCurp, const int* __restrict__ u_off,
    const int* __restrict__ u_item, const float* __restrict__ u_wt,
    float* __restrict__ usum, const void* __restrict__ ueRaw,
    void* __restrict__ outU, int finalMode, int nU, int nEnt,
    const int* __restrict__ flagp) {
    int wid = (blockIdx.x * blockDim.x + threadIdx.x) >> 6;
    int lane = threadIdx.x & 63;
    if (wid >= nU) return;
    float a0 = 0.f, a1 = 0.f;
    int s = u_off[wid], e = u_off[wid + 1];
    for (int j0 = s; j0 < e; j0 += 64) {
        int B = min(64, e - j0);
        int it = (lane < B) ? u_item[j0 + lane] : 0;
        float wv = (lane < B) ? u_wt[j0 + lane] : 0.f;
        int i0 = __shfl(it, 0);
        u32 ev0 = eCurp[(size_t)i0 * 64 + lane];
        u32 ev1 = 0;
        if (B > 1) {
            int i1 = __shfl(it, 1);
            ev1 = eCurp[(size_t)i1 * 64 + lane];
        }
        for (int i = 0; i < B; ++i) {
            u32 cur = ev0;
            ev0 = ev1;
            if (i + 2 < B) {                        // keep 2 loads in flight
                int nx = __shfl(it, i + 2);
                ev1 = eCurp[(size_t)nx * 64 + lane];
            }
            float wc = __shfl(wv, i);
            h2 f = u2h2(cur);
            a0 = fmaf(wc, (float)f.x, a0);
            a1 = fmaf(wc, (float)f.y, a1);
        }
    }
    size_t b32i = (size_t)wid * 64 + lane;
    if (finalMode) {
        int isBf = *flagp;
        const float k = 1.0f / 3.0f;
        size_t be = 2 * b32i;
        float2 us = ((const float2*)usum)[b32i];
        stOut(outU, be, (ldIn(ueRaw, be, isBf) + us.x + a0) * k, isBf);
        stOut(outU, be + 1, (ldIn(ueRaw, be + 1, isBf) + us.y + a1) * k, isBf);
    } else {
        ((float2*)usum)[b32i] = make_float2(a0, a1);
    }
}

extern "C" void kernel_launch(void* const* d_in, const int* in_sizes, int n_in,
                              void* d_out, int out_size, void* d_ws, size_t ws_size,
                              hipStream_t stream) {
    const void* ue  = d_in[1];              // user_emb      [nU,128]
    const void* ee  = d_in[2];              // entity_emb    [nE,128]
    const int*  itr = (const int*)d_in[3];  // inter_edge    [2,Ei]
    const void* iw  = d_in[4];              // inter_edge_w  [Ei]
    const int*  eix = (const int*)d_in[5];  // edge_index    [2,Ee]
    const int*  ety = (const int*)d_in[6];  // edge_type     [Ee]
    const void* rel = d_in[7];              // relation_emb  [10,128]
    const void* wq  = d_in[8];              // W_Q           [128,128]

    const int nU = in_sizes[1] / D;
    const int nE = in_sizes[2] / D;
    const int Ei = in_sizes[4];
    const int Ee = in_sizes[6];
    const int nRel = in_sizes[7] / D;   // 10

    const int* u_idx = itr;            // inter_edge[0] (dest users)
    const int* i_idx = itr + Ei;       // inter_edge[1] (src entities)
    const int* head  = eix;            // edge_index[0] (dest entities)
    const int* tail  = eix + Ee;       // edge_index[1] (src entities)

    char* w = (char*)d_ws;
    auto alloc = [&](size_t bytes) {
        char* p = w;
        w += (bytes + 255) & ~(size_t)255;
        return p;
    };
    int*   flag  = (int*)alloc(256);
    int*  e_off  = (int*)alloc((size_t)(nE + 1) * 4);
    int*  u_off  = (int*)alloc((size_t)(nU + 1) * 4);
    int*  e_pos  = (int*)alloc((size_t)nE * 4);
    int*  u_pos  = (int*)alloc((size_t)nU * 4);
    int*  e_pack = (int*)alloc((size_t)Ee * 4);
    int*  u_item = (int*)alloc((size_t)Ei * 4);
    float* u_wt  = (float*)alloc((size_t)Ei * 4);
    int*  bsumE  = (int*)alloc(64 * 4);
    int*  bsumU  = (int*)alloc(64 * 4);
    u16*  eeb    = (u16*)alloc((size_t)nE * D * 2);        // f16 contig
    u16*  wqh    = (u16*)alloc((size_t)D * D * 2);         // f16
    u16*  relh   = (u16*)alloc((size_t)nRel * D * 2);      // f16
    u16*  eL1    = (u16*)alloc((size_t)nE * D * 2);        // f16 contig
    u16*  PE     = (u16*)alloc((size_t)nE * D * 4);        // interleaved P/E
    float* usum  = (float*)alloc((size_t)nU * D * 4);

    if ((size_t)(w - (char*)d_ws) > ws_size) {
        // Workspace too small. Output stays harness-zeroed.
        // Diagnostic signature: absmax == max|ref| (~6.69), NOT NaN.
        return;
    }

    sniff_k<<<1, 64, 0, stream>>>((const u16*)ue, flag);

    // canonical f16 copies of hot read-only tensors (+ PE E-slots)
    convert_e_k<<<(nE * D + 255) / 256, 256, 0, stream>>>(ee, eeb, PE, nE * D, flag);
    convert_h_k<<<(D * D + 255) / 256, 256, 0, stream>>>(wq, wqh, D * D, flag);
    convert_h_k<<<(nRel * D + 255) / 256, 256, 0, stream>>>(rel, relh, nRel * D, flag);

    // ---- CSR build (structure identical across layers) ----
    const int nbE = (nE + 1023) / 1024;
    const int nbU = (nU + 1023) / 1024;
    zero_k<<<(nE + 1 + 255) / 256, 256, 0, stream>>>(e_off, nE + 1);
    zero_k<<<(nU + 1 + 255) / 256, 256, 0, stream>>>(u_off, nU + 1);
    hist_k<<<(Ee + 255) / 256, 256, 0, stream>>>(head, Ee, nE, e_off);
    hist_k<<<(Ei + 255) / 256, 256, 0, stream>>>(u_idx, Ei, nU, u_off);
    block_sum_k<<<nbE, 256, 0, stream>>>(e_off, nE, bsumE);
    block_sum_k<<<nbU, 256, 0, stream>>>(u_off, nU, bsumU);
    scan_bsums_k<<<1, 64, 0, stream>>>(bsumE, nbE);
    scan_bsums_k<<<1, 64, 0, stream>>>(bsumU, nbU);
    block_scan_k<<<nbE, 256, 0, stream>>>(e_off, nE, bsumE);
    block_scan_k<<<nbU, 256, 0, stream>>>(u_off, nU, bsumU);
    copy_k<<<(nE + 255) / 256, 256, 0, stream>>>(e_off, e_pos, nE);
    copy_k<<<(nU + 255) / 256, 256, 0, stream>>>(u_off, u_pos, nU);
    scatter_e<<<(Ee + 255) / 256, 256, 0, stream>>>(head, tail, ety, Ee, nE, nE,
                                                    e_pos, e_pack);
    scatter_u<<<(Ei + 255) / 256, 256, 0, stream>>>(u_idx, i_idx, iw, Ei, nU, nE,
                                                    u_pos, u_item, u_wt, flag);

    const int entBlocks  = (nE * 64 + 255) / 256;
    const int userBlocks = (nU * 64 + 255) / 256;
    const int gemmBlocks = (nE + GEMM_ROWS - 1) / GEMM_ROWS;

    // ---- layer 1 ----
    gemm_P4<<<gemmBlocks, 256, 0, stream>>>(eeb, wqh, PE, nE);
    entity_agg4<<<entBlocks, 256, 0, stream>>>((const uint2*)PE, relh, e_off, e_pack,
                                               (u32*)eL1, nullptr, nullptr, 0, 0,
                                               nE, flag);
    user_agg4<<<userBlocks, 256, 0, stream>>>((const u32*)eeb, u_off, u_item, u_wt,
                                              usum, nullptr, nullptr, 0, nU, nE, flag);

    // ---- refresh PE E-slots with eL1, then layer 2 (fused mean epilogue) ----
    packE_k<<<(nE * 64 + 255) / 256, 256, 0, stream>>>((const u32*)eL1, (u32*)PE, nE * 64);
    gemm_P4<<<gemmBlocks, 256, 0, stream>>>(eL1, wqh, PE, nE);
    entity_agg4<<<entBlocks, 256, 0, stream>>>((const uint2*)PE, relh, e_off, e_pack,
                                               nullptr, (const u32*)eeb, d_out, 1,
                                               (size_t)nU * D, nE, flag);
    user_agg4<<<userBlocks, 256, 0, stream>>>((const u32*)eL1, u_off, u_item, u_wt,
                                              usum, ue, d_out, 1, nU, nE, flag);
}